// Round 17
// baseline (209.266 us; speedup 1.0000x reference)
//
#include <hip/hip_runtime.h>
#include <hip/hip_bf16.h>
#include <math.h>

#define DIM 256
#define B_SEG 512
#define LN_EPS 1e-5f

typedef __attribute__((ext_vector_type(8))) short bf16x8;
typedef __attribute__((ext_vector_type(4))) float f32x4;

__device__ __forceinline__ float gelu_exact(float v) {
    return 0.5f * v * (1.0f + erff(v * 0.70710678118654752f));
}

__device__ __forceinline__ unsigned int pack2bf(float a, float b) {
    unsigned int ua = (unsigned int)__bfloat16_as_ushort(__float2bfloat16(a));
    unsigned int ub = (unsigned int)__bfloat16_as_ushort(__float2bfloat16(b));
    return ua | (ub << 16);
}

__device__ __forceinline__ float bf2f(short s) {
    return __uint_as_float(((unsigned int)(unsigned short)s) << 16);
}

__device__ __forceinline__ void async16(const void* g, void* l) {
    __builtin_amdgcn_global_load_lds(
        (const __attribute__((address_space(1))) void*)(g),
        (__attribute__((address_space(3))) void*)(l), 16, 0, 0);
}

// ---- Kernel P: weight-prep (blocks 0..255) + bounds (block 256) + zero extra
__global__ __launch_bounds__(256) void k_prep(const float* __restrict__ Wg,
                                              __hip_bfloat16* __restrict__ Wt2,
                                              const int* __restrict__ batch,
                                              int* __restrict__ seg_start,
                                              float* __restrict__ extra, int n) {
    if (blockIdx.x < 256) {
        int k = blockIdx.x;
        int c = threadIdx.x;
        Wt2[((size_t)(k >> 3) << 11) + (c << 3) + (k & 7)] = __float2bfloat16(Wg[(size_t)k * DIM + c]);
        return;
    }
    if (blockIdx.x == 256) {
        for (int s = threadIdx.x; s <= B_SEG; s += 256) {
            int lo = 0, hi = n;
            while (lo < hi) {
                int mid = (lo + hi) >> 1;
                if (batch[mid] < s) lo = mid + 1; else hi = mid;
            }
            seg_start[s] = lo;
        }
        return;
    }
    int b = blockIdx.x - 257;   // 128 blocks zero 'extra' (fallback path only)
    ((float4*)extra)[(size_t)b * 256 + threadIdx.x] = make_float4(0.f, 0.f, 0.f, 0.f);
}

// ---- Kernel C: convert x (fp32) -> xbf (swizzled bf16), unroll x4 -----------
// Little's law: need ~4+ KB reads in flight per CU. 8 dwordx4 loads/wave at
// ~56 VGPR keeps 8 waves/SIMD: 32 waves x 8 x 16B = 4 KB/CU in flight.
__global__ __launch_bounds__(256) void k_convert(const float* __restrict__ x,
                                                 __hip_bfloat16* __restrict__ xbf,
                                                 size_t chunks) {
    const size_t stride = (size_t)gridDim.x * 256;
    size_t g0 = (size_t)blockIdx.x * 256 + threadIdx.x;

    for (; g0 + 3 * stride < chunks; g0 += 4 * stride) {
        float4 v0[4], v1[4];
        #pragma unroll
        for (int j = 0; j < 4; ++j) {
            size_t g = g0 + (size_t)j * stride;
            const float4* p = (const float4*)(x + (g >> 5) * DIM + (int)(g & 31) * 8);
            v0[j] = p[0];
            v1[j] = p[1];
        }
        #pragma unroll
        for (int j = 0; j < 4; ++j) {
            size_t g = g0 + (size_t)j * stride;
            size_t r = g >> 5;
            int    c = (int)(g & 31);
            uint4 pk;
            pk.x = pack2bf(v0[j].x, v0[j].y); pk.y = pack2bf(v0[j].z, v0[j].w);
            pk.z = pack2bf(v1[j].x, v1[j].y); pk.w = pack2bf(v1[j].z, v1[j].w);
            *(uint4*)((char*)xbf + r * 512 + ((c * 16) ^ ((int)(r & 7) << 4))) = pk;
        }
    }
    for (; g0 < chunks; g0 += stride) {
        size_t r = g0 >> 5;
        int    c = (int)(g0 & 31);
        const float4* p = (const float4*)(x + r * DIM + c * 8);
        float4 v0 = p[0];
        float4 v1 = p[1];
        uint4 pk;
        pk.x = pack2bf(v0.x, v0.y); pk.y = pack2bf(v0.z, v0.w);
        pk.z = pack2bf(v1.x, v1.y); pk.w = pack2bf(v1.z, v1.w);
        *(uint4*)((char*)xbf + r * 512 + ((c * 16) ^ ((int)(r & 7) << 4))) = pk;
    }
}

// ---- Kernel 2: per-segment VN pipeline; head gathers the segment sum --------
__global__ __launch_bounds__(256) void k_vn(const __hip_bfloat16* __restrict__ xbf,
                                            const float* __restrict__ extra,  // fallback sums [B][D]
                                            const int* __restrict__ seg_start,
                                            const float* __restrict__ vn_embed,
                                            const float* __restrict__ W1, const float* __restrict__ b1,
                                            const float* __restrict__ g1, const float* __restrict__ be1,
                                            const float* __restrict__ W2, const float* __restrict__ b2,
                                            const float* __restrict__ g2, const float* __restrict__ be2,
                                            const float* __restrict__ Wg, const float* __restrict__ bg,
                                            float* __restrict__ vn_state_out, // [B,D]
                                            float* __restrict__ nu,           // ws [B,D]
                                            float* __restrict__ gpart,        // ws [B,D]
                                            int use_bf) {
    __shared__ float sIn[DIM];
    __shared__ float sRed[DIM];
    __shared__ float sRed2[DIM];
    __shared__ float sG[8 * DIM];   // 8 KB gather-reduce buffer
    const int b = blockIdx.x;
    const int d = threadIdx.x;

    const int s0 = seg_start[b], s1 = seg_start[b + 1];
    float sum;
    if (use_bf) {
        const int h  = threadIdx.x >> 5;   // 0..7 row-parity class
        const int li = threadIdx.x & 31;   // 16B chunk (8 dims)
        float acc[8] = {0.f, 0.f, 0.f, 0.f, 0.f, 0.f, 0.f, 0.f};
        for (int r = s0 + h; r < s1; r += 8) {
            bf16x8 w = *(const bf16x8*)((const char*)xbf + (size_t)r * 512 +
                                        ((li * 16) ^ ((r & 7) << 4)));
            #pragma unroll
            for (int e = 0; e < 8; ++e) acc[e] += bf2f(w[e]);
        }
        #pragma unroll
        for (int e = 0; e < 8; ++e) sG[h * DIM + li * 8 + e] = acc[e];
        __syncthreads();
        float s = 0.f;
        #pragma unroll
        for (int h2 = 0; h2 < 8; ++h2) s += sG[h2 * DIM + d];
        sum = s;
    } else {
        sum = extra[(size_t)b * DIM + d];
    }
    float denom = fmaxf((float)(s1 - s0), 1.0f);
    sIn[d] = sum / denom;
    __syncthreads();

    float h0 = 0.f, h1 = 0.f, h2a = 0.f, h3 = 0.f;
    for (int k = 0; k < DIM; k += 4) {
        h0  = fmaf(sIn[k + 0], W1[(size_t)(k + 0) * DIM + d], h0);
        h1  = fmaf(sIn[k + 1], W1[(size_t)(k + 1) * DIM + d], h1);
        h2a = fmaf(sIn[k + 2], W1[(size_t)(k + 2) * DIM + d], h2a);
        h3  = fmaf(sIn[k + 3], W1[(size_t)(k + 3) * DIM + d], h3);
    }
    float h = gelu_exact(b1[d] + ((h0 + h1) + (h2a + h3)));

    sRed[d] = h; sRed2[d] = h * h;
    __syncthreads();
    for (int s = 128; s > 0; s >>= 1) {
        if (d < s) { sRed[d] += sRed[d + s]; sRed2[d] += sRed2[d + s]; }
        __syncthreads();
    }
    float mu = sRed[0] * (1.0f / DIM);
    float var = fmaxf(sRed2[0] * (1.0f / DIM) - mu * mu, 0.0f);
    float rs = rsqrtf(var + LN_EPS);
    float vnst = vn_embed[d] + ((h - mu) * rs * g1[d] + be1[d]);
    vn_state_out[(size_t)b * DIM + d] = vnst;
    __syncthreads();
    sIn[d] = vnst;
    __syncthreads();

    float g0 = 0.f, g1a = 0.f, g2a = 0.f, g3 = 0.f;
    for (int k = 0; k < DIM; k += 4) {
        g0  = fmaf(sIn[k + 0], W2[(size_t)(k + 0) * DIM + d], g0);
        g1a = fmaf(sIn[k + 1], W2[(size_t)(k + 1) * DIM + d], g1a);
        g2a = fmaf(sIn[k + 2], W2[(size_t)(k + 2) * DIM + d], g2a);
        g3  = fmaf(sIn[k + 3], W2[(size_t)(k + 3) * DIM + d], g3);
    }
    float h2 = gelu_exact(b2[d] + ((g0 + g1a) + (g2a + g3)));

    sRed[d] = h2; sRed2[d] = h2 * h2;
    __syncthreads();
    for (int s = 128; s > 0; s >>= 1) {
        if (d < s) { sRed[d] += sRed[d + s]; sRed2[d] += sRed2[d + s]; }
        __syncthreads();
    }
    float mu2 = sRed[0] * (1.0f / DIM);
    float var2 = fmaxf(sRed2[0] * (1.0f / DIM) - mu2 * mu2, 0.0f);
    float rs2 = rsqrtf(var2 + LN_EPS);
    float nud = (h2 - mu2) * rs2 * g2[d] + be2[d];
    nu[(size_t)b * DIM + d] = nud;
    __syncthreads();
    sIn[d] = nud;
    __syncthreads();

    float p0 = 0.f, p1 = 0.f, p2 = 0.f, p3 = 0.f;
    for (int k = 0; k < DIM; k += 4) {
        p0 = fmaf(sIn[k + 0], Wg[(size_t)(DIM + k + 0) * DIM + d], p0);
        p1 = fmaf(sIn[k + 1], Wg[(size_t)(DIM + k + 1) * DIM + d], p1);
        p2 = fmaf(sIn[k + 2], Wg[(size_t)(DIM + k + 2) * DIM + d], p2);
        p3 = fmaf(sIn[k + 3], Wg[(size_t)(DIM + k + 3) * DIM + d], p3);
    }
    gpart[(size_t)b * DIM + d] = bg[d] + ((p0 + p1) + (p2 + p3));
}

// ---- Kernel 3a (bf16 path): gate GEMM, A via global_load_lds from xbf --------
__global__ __launch_bounds__(256, 4) void k_gate_bf(const __hip_bfloat16* __restrict__ xbf,
                                                    const int* __restrict__ batch,
                                                    const __hip_bfloat16* __restrict__ Wt2,
                                                    const float* __restrict__ nu,    // [B,D]
                                                    const float* __restrict__ gpart, // [B,D]
                                                    float* __restrict__ xout,
                                                    int n) {
    __shared__ __align__(16) char sA[64 * 512];   // 32 KB, pre-swizzled rows

    const int tid  = threadIdx.x;
    const int wave = tid >> 6;
    const int lane = tid & 63;
    const int r15  = lane & 15;
    const int kq   = lane >> 4;
    const size_t i0 = (size_t)blockIdx.x * 64;

    const char* gsrc = (const char*)xbf + i0 * 512;
    #pragma unroll
    for (int j = 0; j < 8; ++j)
        async16(gsrc + j * 4096 + tid * 16, sA + j * 4096 + wave * 1024);
    __syncthreads();

    f32x4 acc[4][4];
    #pragma unroll
    for (int m = 0; m < 4; ++m)
        #pragma unroll
        for (int nn = 0; nn < 4; ++nn)
            acc[m][nn] = (f32x4){0.f, 0.f, 0.f, 0.f};

    #pragma unroll
    for (int ks = 0; ks < 8; ++ks) {
        bf16x8 a[4], b[4];
        #pragma unroll
        for (int nn = 0; nn < 4; ++nn) {
            int c = wave * 64 + nn * 16 + r15;
            b[nn] = *(const bf16x8*)(Wt2 + ((size_t)(ks * 4 + kq) << 11) + (c << 3));
        }
        #pragma unroll
        for (int m = 0; m < 4; ++m) {
            int r = m * 16 + r15;
            a[m] = *(const bf16x8*)(sA + r * 512 + ((ks * 64 + kq * 16) ^ ((r & 7) << 4)));
        }
        #pragma unroll
        for (int m = 0; m < 4; ++m)
            #pragma unroll
            for (int nn = 0; nn < 4; ++nn)
                acc[m][nn] = __builtin_amdgcn_mfma_f32_16x16x32_bf16(a[m], b[nn], acc[m][nn], 0, 0, 0);
    }

    #pragma unroll
    for (int m = 0; m < 4; ++m) {
        #pragma unroll
        for (int q = 0; q < 4; ++q) {
            int rr = m * 16 + kq * 4 + q;
            long node = (long)(i0 + rr);
            if (node >= n) continue;
            int bb = batch[node];
            #pragma unroll
            for (int nn = 0; nn < 4; ++nn) {
                int col = wave * 64 + nn * 16 + r15;
                float pre = acc[m][nn][q] + gpart[bb * DIM + col];
                float e = __expf(-pre);
                float gte = __builtin_amdgcn_rcpf(1.0f + e);
                float xres = __bfloat162float(
                    *(const __hip_bfloat16*)(sA + rr * 512 + ((2 * col) ^ ((rr & 7) << 4))));
                xout[(size_t)node * DIM + col] = xres + gte * nu[bb * DIM + col];
            }
        }
    }
}

// ---- Fallback kernels (used only if ws too small for xbf) -------------------
__global__ __launch_bounds__(256) void k_segsum_fp(const float* __restrict__ x,
                                                   const int* __restrict__ batch,
                                                   float* __restrict__ sums,
                                                   int n) {
    const int i0 = blockIdx.x * 64;
    if (i0 >= n) return;
    const int t    = threadIdx.x;
    const int lane = t & 63;
    const int d4   = lane * 4;
    const int rg   = t >> 6;
    float4 acc = make_float4(0.f, 0.f, 0.f, 0.f);
    int cur = -1;
    for (int j = 0; j < 16; ++j) {
        int i = i0 + rg + 4 * j;
        if (i >= n) break;
        int b = batch[i];
        if (b != cur) {
            if (cur >= 0) {
                atomicAdd(&sums[(size_t)cur * DIM + d4 + 0], acc.x);
                atomicAdd(&sums[(size_t)cur * DIM + d4 + 1], acc.y);
                atomicAdd(&sums[(size_t)cur * DIM + d4 + 2], acc.z);
                atomicAdd(&sums[(size_t)cur * DIM + d4 + 3], acc.w);
            }
            acc = make_float4(0.f, 0.f, 0.f, 0.f);
            cur = b;
        }
        float4 v = *(const float4*)(x + (size_t)i * DIM + d4);
        acc.x += v.x; acc.y += v.y; acc.z += v.z; acc.w += v.w;
    }
    if (cur >= 0) {
        atomicAdd(&sums[(size_t)cur * DIM + d4 + 0], acc.x);
        atomicAdd(&sums[(size_t)cur * DIM + d4 + 1], acc.y);
        atomicAdd(&sums[(size_t)cur * DIM + d4 + 2], acc.z);
        atomicAdd(&sums[(size_t)cur * DIM + d4 + 3], acc.w);
    }
}

__global__ __launch_bounds__(256) void k_gate_fp(const float* __restrict__ x,
                                                 const int* __restrict__ batch,
                                                 const __hip_bfloat16* __restrict__ Wt2,
                                                 const float* __restrict__ nu,
                                                 const float* __restrict__ gpart,
                                                 float* __restrict__ xout,
                                                 int n) {
    __shared__ __align__(16) char sA[32 * 512];
    const int tid  = threadIdx.x;
    const int wave = tid >> 6;
    const int lane = tid & 63;
    const int r15  = lane & 15;
    const int kq   = lane >> 4;
    const int i0   = blockIdx.x * 32;

    float4 av0[4], av1[4];
    #pragma unroll
    for (int j = 0; j < 4; ++j) {
        int v = j * 256 + tid;
        int r = v >> 5;
        int k8 = v & 31;
        int node = i0 + r;
        if (node < n) {
            const float* p = x + (size_t)node * DIM + k8 * 8;
            av0[j] = *(const float4*)p;
            av1[j] = *(const float4*)(p + 4);
        } else {
            av0[j] = make_float4(0.f, 0.f, 0.f, 0.f);
            av1[j] = av0[j];
        }
    }
    #pragma unroll
    for (int j = 0; j < 4; ++j) {
        int v = j * 256 + tid;
        int r = v >> 5;
        int k8 = v & 31;
        uint4 pk;
        pk.x = pack2bf(av0[j].x, av0[j].y);
        pk.y = pack2bf(av0[j].z, av0[j].w);
        pk.z = pack2bf(av1[j].x, av1[j].y);
        pk.w = pack2bf(av1[j].z, av1[j].w);
        *(uint4*)(sA + r * 512 + ((k8 * 16) ^ ((r & 7) << 4))) = pk;
    }
    __syncthreads();

    f32x4 acc[2][4];
    #pragma unroll
    for (int m = 0; m < 2; ++m)
        #pragma unroll
        for (int nn = 0; nn < 4; ++nn)
            acc[m][nn] = (f32x4){0.f, 0.f, 0.f, 0.f};

    #pragma unroll
    for (int ks = 0; ks < 8; ++ks) {
        bf16x8 a[2], b[4];
        #pragma unroll
        for (int nn = 0; nn < 4; ++nn) {
            int c = wave * 64 + nn * 16 + r15;
            b[nn] = *(const bf16x8*)(Wt2 + ((size_t)(ks * 4 + kq) << 11) + (c << 3));
        }
        #pragma unroll
        for (int m = 0; m < 2; ++m) {
            int r = m * 16 + r15;
            a[m] = *(const bf16x8*)(sA + r * 512 + ((ks * 64 + kq * 16) ^ ((r & 7) << 4)));
        }
        #pragma unroll
        for (int m = 0; m < 2; ++m)
            #pragma unroll
            for (int nn = 0; nn < 4; ++nn)
                acc[m][nn] = __builtin_amdgcn_mfma_f32_16x16x32_bf16(a[m], b[nn], acc[m][nn], 0, 0, 0);
    }

    #pragma unroll
    for (int m = 0; m < 2; ++m) {
        #pragma unroll
        for (int q = 0; q < 4; ++q) {
            int rr = m * 16 + kq * 4 + q;
            int node = i0 + rr;
            if (node >= n) continue;
            int bb = batch[node];
            #pragma unroll
            for (int nn = 0; nn < 4; ++nn) {
                int col = wave * 64 + nn * 16 + r15;
                float pre = acc[m][nn][q] + gpart[bb * DIM + col];
                float e = __expf(-pre);
                float gte = __builtin_amdgcn_rcpf(1.0f + e);
                float xres = __bfloat162float(
                    *(const __hip_bfloat16*)(sA + rr * 512 + ((2 * col) ^ ((rr & 7) << 4))));
                xout[(size_t)node * DIM + col] = xres + gte * nu[bb * DIM + col];
            }
        }
    }
}

extern "C" void kernel_launch(void* const* d_in, const int* in_sizes, int n_in,
                              void* d_out, int out_size, void* d_ws, size_t ws_size,
                              hipStream_t stream) {
    const float* x        = (const float*)d_in[0];
    const int*   batch    = (const int*)d_in[1];
    const float* vn_embed = (const float*)d_in[2];
    const float* W1  = (const float*)d_in[3];
    const float* b1  = (const float*)d_in[4];
    const float* g1  = (const float*)d_in[5];
    const float* be1 = (const float*)d_in[6];
    const float* W2  = (const float*)d_in[7];
    const float* b2  = (const float*)d_in[8];
    const float* g2  = (const float*)d_in[9];
    const float* be2 = (const float*)d_in[10];
    const float* Wg  = (const float*)d_in[11];
    const float* bg  = (const float*)d_in[12];

    const int n = in_sizes[0] / DIM;
    const int nt64 = (n + 63) / 64;

    float* out = (float*)d_out;
    float* xout = out;                              // [N,D]
    float* vn_state_out = out + (size_t)n * DIM;    // [B,D]

    // ws layout
    char* wsb = (char*)d_ws;
    int*   seg_start = (int*)wsb;                               // 4 KB
    float* extra     = (float*)(wsb + 4096);                    // 512 KB (fallback sums)
    float* nu        = extra + (size_t)B_SEG * DIM;             // 512 KB
    float* gpart     = nu + (size_t)B_SEG * DIM;                // 512 KB
    __hip_bfloat16* Wt2 = (__hip_bfloat16*)(gpart + (size_t)B_SEG * DIM); // 128 KB
    __hip_bfloat16* xbf = Wt2 + (size_t)DIM * DIM;

    const size_t xbf_off = (size_t)((char*)xbf - wsb);
    const size_t need = xbf_off + (size_t)nt64 * 64 * 512;
    const bool use_bf = (ws_size >= need);

    k_prep<<<385, 256, 0, stream>>>(Wg, Wt2, batch, seg_start, extra, n);

    if (use_bf) {
        const size_t chunks = (size_t)n * 32;
        k_convert<<<2048, 256, 0, stream>>>(x, xbf, chunks);
    } else {
        k_segsum_fp<<<nt64, 256, 0, stream>>>(x, batch, extra, n);
    }

    k_vn<<<B_SEG, 256, 0, stream>>>(xbf, extra, seg_start, vn_embed,
                                    W1, b1, g1, be1,
                                    W2, b2, g2, be2,
                                    Wg, bg,
                                    vn_state_out, nu, gpart,
                                    use_bf ? 1 : 0);

    if (use_bf) {
        k_gate_bf<<<nt64, 256, 0, stream>>>(xbf, batch, Wt2, nu, gpart, xout, n);
    } else {
        int nblk3 = (n + 31) / 32;
        k_gate_fp<<<nblk3, 256, 0, stream>>>(x, batch, Wt2, nu, gpart, xout, n);
    }
}

// Round 18
// 192.267 us; speedup vs baseline: 1.0884x; 1.0884x over previous
//
#include <hip/hip_runtime.h>
#include <hip/hip_bf16.h>
#include <math.h>

#define DIM 256
#define B_SEG 512
#define LN_EPS 1e-5f

typedef __attribute__((ext_vector_type(8))) short bf16x8;
typedef __attribute__((ext_vector_type(4))) float f32x4;

__device__ __forceinline__ float gelu_exact(float v) {
    return 0.5f * v * (1.0f + erff(v * 0.70710678118654752f));
}

__device__ __forceinline__ unsigned int pack2bf(float a, float b) {
    unsigned int ua = (unsigned int)__bfloat16_as_ushort(__float2bfloat16(a));
    unsigned int ub = (unsigned int)__bfloat16_as_ushort(__float2bfloat16(b));
    return ua | (ub << 16);
}

__device__ __forceinline__ void async16(const void* g, void* l) {
    __builtin_amdgcn_global_load_lds(
        (const __attribute__((address_space(1))) void*)(g),
        (__attribute__((address_space(3))) void*)(l), 16, 0, 0);
}

// ---- Kernel P: weight-prep (blocks 0..255) + bounds (block 256) + zero extra
__global__ __launch_bounds__(256) void k_prep(const float* __restrict__ Wg,
                                              __hip_bfloat16* __restrict__ Wt2,
                                              const int* __restrict__ batch,
                                              int* __restrict__ seg_start,
                                              float* __restrict__ extra, int n) {
    if (blockIdx.x < 256) {
        int k = blockIdx.x;
        int c = threadIdx.x;
        Wt2[((size_t)(k >> 3) << 11) + (c << 3) + (k & 7)] = __float2bfloat16(Wg[(size_t)k * DIM + c]);
        return;
    }
    if (blockIdx.x == 256) {
        for (int s = threadIdx.x; s <= B_SEG; s += 256) {
            int lo = 0, hi = n;
            while (lo < hi) {
                int mid = (lo + hi) >> 1;
                if (batch[mid] < s) lo = mid + 1; else hi = mid;
            }
            seg_start[s] = lo;
        }
        return;
    }
    int b = blockIdx.x - 257;   // 128 blocks zero 'extra' (512 KB)
    ((float4*)extra)[(size_t)b * 256 + threadIdx.x] = make_float4(0.f, 0.f, 0.f, 0.f);
}

// ---- Kernel 1: 32-row DMA tile -> {swizzled bf16 xbf (16B stores), partials} -
// 36 KB LDS -> 4 blocks/CU. part[t] = sum of rows in tile-first segment;
// boundary-tile tail -> 256 atomics (rare); middle -> essentially never.
// Flush sites guarded to lanes 0-31 of wave 0 ONLY (r12 double-count fix).
__global__ __launch_bounds__(256, 4) void k_pass1(const float* __restrict__ x,
                                                  const int* __restrict__ batch,
                                                  float* __restrict__ part,   // [nt32][D]
                                                  float* __restrict__ extra,  // [B][D] zeroed
                                                  __hip_bfloat16* __restrict__ xbf,
                                                  int n) {
    __shared__ __align__(16) char sX[32 * 1024];   // 32 KB fp32 tile
    __shared__ float4 red[4][32][2];               // 4 KB reduce buffer

    const int tile = blockIdx.x;
    const int i0   = tile * 32;
    if (i0 >= n) return;
    const int iN   = min(i0 + 32, n);

    const int tid  = threadIdx.x;
    const int wave = tid >> 6;
    const int lane = tid & 63;
    const int li   = lane & 31;
    const int sub  = lane >> 5;

    if (iN - i0 == 32) {
        const char* g = (const char*)x + (size_t)i0 * 1024;
        #pragma unroll
        for (int j = 0; j < 8; ++j)
            async16(g + j * 4096 + tid * 16, sX + j * 4096 + wave * 1024);
    } else {
        for (int v = tid; v < 32 * 64; v += 256) {
            int r = v >> 6, c = v & 63;
            float4 val = (i0 + r < n) ? ((const float4*)(x + (size_t)(i0 + r) * DIM))[c]
                                      : make_float4(0.f, 0.f, 0.f, 0.f);
            *(float4*)(sX + r * 1024 + c * 16) = val;
        }
    }
    const int sf = batch[i0];
    const int sl = batch[iN - 1];
    int bt[4];
    #pragma unroll
    for (int jj = 0; jj < 4; ++jj) {
        int gr = i0 + wave * 8 + jj * 2 + sub;
        bt[jj] = (gr < n) ? batch[gr] : -2;
    }
    __syncthreads();   // drains DMA

    float4 a0 = make_float4(0.f,0.f,0.f,0.f), a1 = a0, b0 = a0, b1 = a0;
    #pragma unroll
    for (int jj = 0; jj < 4; ++jj) {
        const int r  = wave * 8 + jj * 2 + sub;
        const int gr = i0 + r;
        float4 v0 = *(const float4*)(sX + r * 1024 + li * 32);
        float4 v1 = *(const float4*)(sX + r * 1024 + li * 32 + 16);
        if (gr < n) {
            uint4 pk;
            pk.x = pack2bf(v0.x, v0.y); pk.y = pack2bf(v0.z, v0.w);
            pk.z = pack2bf(v1.x, v1.y); pk.w = pack2bf(v1.z, v1.w);
            *(uint4*)((char*)xbf + (size_t)gr * 512 + ((li * 16) ^ ((r & 7) << 4))) = pk;
        }
        const int b = bt[jj];
        if (b == sf) {
            a0.x += v0.x; a0.y += v0.y; a0.z += v0.z; a0.w += v0.w;
            a1.x += v1.x; a1.y += v1.y; a1.z += v1.z; a1.w += v1.w;
        } else if (b == sl) {
            b0.x += v0.x; b0.y += v0.y; b0.z += v0.z; b0.w += v0.w;
            b1.x += v1.x; b1.y += v1.y; b1.z += v1.z; b1.w += v1.w;
        } else if (gr < n) {   // middle segment: essentially never
            float* e = &extra[(size_t)b * DIM + li * 8];
            atomicAdd(e + 0, v0.x); atomicAdd(e + 1, v0.y);
            atomicAdd(e + 2, v0.z); atomicAdd(e + 3, v0.w);
            atomicAdd(e + 4, v1.x); atomicAdd(e + 5, v1.y);
            atomicAdd(e + 6, v1.z); atomicAdd(e + 7, v1.w);
        }
    }

    // fold sub halves (lane ^ 32)
    a0.x += __shfl_xor(a0.x, 32); a0.y += __shfl_xor(a0.y, 32);
    a0.z += __shfl_xor(a0.z, 32); a0.w += __shfl_xor(a0.w, 32);
    a1.x += __shfl_xor(a1.x, 32); a1.y += __shfl_xor(a1.y, 32);
    a1.z += __shfl_xor(a1.z, 32); a1.w += __shfl_xor(a1.w, 32);

    if (sub == 0) { red[wave][li][0] = a0; red[wave][li][1] = a1; }
    __syncthreads();
    if (wave == 0 && sub == 0) {     // lanes 0-31 only
        #pragma unroll
        for (int half = 0; half < 2; ++half) {
            float4 r0 = red[0][li][half], r1 = red[1][li][half],
                   r2 = red[2][li][half], r3 = red[3][li][half];
            float4 t;
            t.x = (r0.x + r1.x) + (r2.x + r3.x);
            t.y = (r0.y + r1.y) + (r2.y + r3.y);
            t.z = (r0.z + r1.z) + (r2.z + r3.z);
            t.w = (r0.w + r1.w) + (r2.w + r3.w);
            *(float4*)(part + (size_t)tile * DIM + li * 8 + half * 4) = t;
        }
    }

    if (sf != sl) {   // boundary tile (~511 of 6250): tail segment via atomics
        b0.x += __shfl_xor(b0.x, 32); b0.y += __shfl_xor(b0.y, 32);
        b0.z += __shfl_xor(b0.z, 32); b0.w += __shfl_xor(b0.w, 32);
        b1.x += __shfl_xor(b1.x, 32); b1.y += __shfl_xor(b1.y, 32);
        b1.z += __shfl_xor(b1.z, 32); b1.w += __shfl_xor(b1.w, 32);
        __syncthreads();
        if (sub == 0) { red[wave][li][0] = b0; red[wave][li][1] = b1; }
        __syncthreads();
        if (wave == 0 && sub == 0) {   // lanes 0-31 only (r12 fix)
            float* e = &extra[(size_t)sl * DIM + li * 8];
            #pragma unroll
            for (int half = 0; half < 2; ++half) {
                float4 r0 = red[0][li][half], r1 = red[1][li][half],
                       r2 = red[2][li][half], r3 = red[3][li][half];
                atomicAdd(e + half * 4 + 0, (r0.x + r1.x) + (r2.x + r3.x));
                atomicAdd(e + half * 4 + 1, (r0.y + r1.y) + (r2.y + r3.y));
                atomicAdd(e + half * 4 + 2, (r0.z + r1.z) + (r2.z + r3.z));
                atomicAdd(e + half * 4 + 3, (r0.w + r1.w) + (r2.w + r3.w));
            }
        }
    }
}

// ---------------- Kernel 2: per-segment VN pipeline (part-gather head) --------
__global__ __launch_bounds__(256) void k_vn(const float* __restrict__ part,   // [nt32][D]
                                            const float* __restrict__ extra,  // [B][D]
                                            const int* __restrict__ seg_start,
                                            const float* __restrict__ vn_embed,
                                            const float* __restrict__ W1, const float* __restrict__ b1,
                                            const float* __restrict__ g1, const float* __restrict__ be1,
                                            const float* __restrict__ W2, const float* __restrict__ b2,
                                            const float* __restrict__ g2, const float* __restrict__ be2,
                                            const float* __restrict__ Wg, const float* __restrict__ bg,
                                            float* __restrict__ vn_state_out, // [B,D]
                                            float* __restrict__ nu,           // ws [B,D]
                                            float* __restrict__ gpart,        // ws [B,D]
                                            int use_parts) {
    __shared__ float sIn[DIM];
    __shared__ float sRed[DIM];
    __shared__ float sRed2[DIM];
    const int b = blockIdx.x;
    const int d = threadIdx.x;

    const int s0 = seg_start[b], s1 = seg_start[b + 1];
    float sum = extra[(size_t)b * DIM + d];
    if (use_parts) {
        const int t0 = (s0 + 31) >> 5, t1 = (s1 + 31) >> 5;
        for (int t = t0; t < t1; ++t) sum += part[(size_t)t * DIM + d];
    }
    float denom = fmaxf((float)(s1 - s0), 1.0f);
    sIn[d] = sum / denom;
    __syncthreads();

    float h0 = 0.f, h1 = 0.f, h2a = 0.f, h3 = 0.f;
    for (int k = 0; k < DIM; k += 4) {
        h0  = fmaf(sIn[k + 0], W1[(size_t)(k + 0) * DIM + d], h0);
        h1  = fmaf(sIn[k + 1], W1[(size_t)(k + 1) * DIM + d], h1);
        h2a = fmaf(sIn[k + 2], W1[(size_t)(k + 2) * DIM + d], h2a);
        h3  = fmaf(sIn[k + 3], W1[(size_t)(k + 3) * DIM + d], h3);
    }
    float h = gelu_exact(b1[d] + ((h0 + h1) + (h2a + h3)));

    sRed[d] = h; sRed2[d] = h * h;
    __syncthreads();
    for (int s = 128; s > 0; s >>= 1) {
        if (d < s) { sRed[d] += sRed[d + s]; sRed2[d] += sRed2[d + s]; }
        __syncthreads();
    }
    float mu = sRed[0] * (1.0f / DIM);
    float var = fmaxf(sRed2[0] * (1.0f / DIM) - mu * mu, 0.0f);
    float rs = rsqrtf(var + LN_EPS);
    float vnst = vn_embed[d] + ((h - mu) * rs * g1[d] + be1[d]);
    vn_state_out[(size_t)b * DIM + d] = vnst;
    __syncthreads();
    sIn[d] = vnst;
    __syncthreads();

    float g0 = 0.f, g1a = 0.f, g2a = 0.f, g3 = 0.f;
    for (int k = 0; k < DIM; k += 4) {
        g0  = fmaf(sIn[k + 0], W2[(size_t)(k + 0) * DIM + d], g0);
        g1a = fmaf(sIn[k + 1], W2[(size_t)(k + 1) * DIM + d], g1a);
        g2a = fmaf(sIn[k + 2], W2[(size_t)(k + 2) * DIM + d], g2a);
        g3  = fmaf(sIn[k + 3], W2[(size_t)(k + 3) * DIM + d], g3);
    }
    float h2 = gelu_exact(b2[d] + ((g0 + g1a) + (g2a + g3)));

    sRed[d] = h2; sRed2[d] = h2 * h2;
    __syncthreads();
    for (int s = 128; s > 0; s >>= 1) {
        if (d < s) { sRed[d] += sRed[d + s]; sRed2[d] += sRed2[d + s]; }
        __syncthreads();
    }
    float mu2 = sRed[0] * (1.0f / DIM);
    float var2 = fmaxf(sRed2[0] * (1.0f / DIM) - mu2 * mu2, 0.0f);
    float rs2 = rsqrtf(var2 + LN_EPS);
    float nud = (h2 - mu2) * rs2 * g2[d] + be2[d];
    nu[(size_t)b * DIM + d] = nud;
    __syncthreads();
    sIn[d] = nud;
    __syncthreads();

    float p0 = 0.f, p1 = 0.f, p2 = 0.f, p3 = 0.f;
    for (int k = 0; k < DIM; k += 4) {
        p0 = fmaf(sIn[k + 0], Wg[(size_t)(DIM + k + 0) * DIM + d], p0);
        p1 = fmaf(sIn[k + 1], Wg[(size_t)(DIM + k + 1) * DIM + d], p1);
        p2 = fmaf(sIn[k + 2], Wg[(size_t)(DIM + k + 2) * DIM + d], p2);
        p3 = fmaf(sIn[k + 3], Wg[(size_t)(DIM + k + 3) * DIM + d], p3);
    }
    gpart[(size_t)b * DIM + d] = bg[d] + ((p0 + p1) + (p2 + p3));
}

// ---- Kernel 3a (bf16 path): gate GEMM, A via global_load_lds from xbf --------
__global__ __launch_bounds__(256, 4) void k_gate_bf(const __hip_bfloat16* __restrict__ xbf,
                                                    const int* __restrict__ batch,
                                                    const __hip_bfloat16* __restrict__ Wt2,
                                                    const float* __restrict__ nu,    // [B,D]
                                                    const float* __restrict__ gpart, // [B,D]
                                                    float* __restrict__ xout,
                                                    int n) {
    __shared__ __align__(16) char sA[64 * 512];   // 32 KB, pre-swizzled rows

    const int tid  = threadIdx.x;
    const int wave = tid >> 6;
    const int lane = tid & 63;
    const int r15  = lane & 15;
    const int kq   = lane >> 4;
    const size_t i0 = (size_t)blockIdx.x * 64;

    const char* gsrc = (const char*)xbf + i0 * 512;
    #pragma unroll
    for (int j = 0; j < 8; ++j)
        async16(gsrc + j * 4096 + tid * 16, sA + j * 4096 + wave * 1024);
    __syncthreads();

    f32x4 acc[4][4];
    #pragma unroll
    for (int m = 0; m < 4; ++m)
        #pragma unroll
        for (int nn = 0; nn < 4; ++nn)
            acc[m][nn] = (f32x4){0.f, 0.f, 0.f, 0.f};

    #pragma unroll
    for (int ks = 0; ks < 8; ++ks) {
        bf16x8 a[4], b[4];
        #pragma unroll
        for (int nn = 0; nn < 4; ++nn) {
            int c = wave * 64 + nn * 16 + r15;
            b[nn] = *(const bf16x8*)(Wt2 + ((size_t)(ks * 4 + kq) << 11) + (c << 3));
        }
        #pragma unroll
        for (int m = 0; m < 4; ++m) {
            int r = m * 16 + r15;
            a[m] = *(const bf16x8*)(sA + r * 512 + ((ks * 64 + kq * 16) ^ ((r & 7) << 4)));
        }
        #pragma unroll
        for (int m = 0; m < 4; ++m)
            #pragma unroll
            for (int nn = 0; nn < 4; ++nn)
                acc[m][nn] = __builtin_amdgcn_mfma_f32_16x16x32_bf16(a[m], b[nn], acc[m][nn], 0, 0, 0);
    }

    #pragma unroll
    for (int m = 0; m < 4; ++m) {
        #pragma unroll
        for (int q = 0; q < 4; ++q) {
            int rr = m * 16 + kq * 4 + q;
            long node = (long)(i0 + rr);
            if (node >= n) continue;
            int bb = batch[node];
            #pragma unroll
            for (int nn = 0; nn < 4; ++nn) {
                int col = wave * 64 + nn * 16 + r15;
                float pre = acc[m][nn][q] + gpart[bb * DIM + col];
                float e = __expf(-pre);
                float gte = __builtin_amdgcn_rcpf(1.0f + e);
                float xres = __bfloat162float(
                    *(const __hip_bfloat16*)(sA + rr * 512 + ((2 * col) ^ ((rr & 7) << 4))));
                xout[(size_t)node * DIM + col] = xres + gte * nu[bb * DIM + col];
            }
        }
    }
}

// ---- Fallback kernels (used only if ws too small for xbf) -------------------
__global__ __launch_bounds__(256) void k_segsum_fp(const float* __restrict__ x,
                                                   const int* __restrict__ batch,
                                                   float* __restrict__ sums,
                                                   int n) {
    const int i0 = blockIdx.x * 64;
    if (i0 >= n) return;
    const int t    = threadIdx.x;
    const int lane = t & 63;
    const int d4   = lane * 4;
    const int rg   = t >> 6;
    float4 acc = make_float4(0.f, 0.f, 0.f, 0.f);
    int cur = -1;
    for (int j = 0; j < 16; ++j) {
        int i = i0 + rg + 4 * j;
        if (i >= n) break;
        int b = batch[i];
        if (b != cur) {
            if (cur >= 0) {
                atomicAdd(&sums[(size_t)cur * DIM + d4 + 0], acc.x);
                atomicAdd(&sums[(size_t)cur * DIM + d4 + 1], acc.y);
                atomicAdd(&sums[(size_t)cur * DIM + d4 + 2], acc.z);
                atomicAdd(&sums[(size_t)cur * DIM + d4 + 3], acc.w);
            }
            acc = make_float4(0.f, 0.f, 0.f, 0.f);
            cur = b;
        }
        float4 v = *(const float4*)(x + (size_t)i * DIM + d4);
        acc.x += v.x; acc.y += v.y; acc.z += v.z; acc.w += v.w;
    }
    if (cur >= 0) {
        atomicAdd(&sums[(size_t)cur * DIM + d4 + 0], acc.x);
        atomicAdd(&sums[(size_t)cur * DIM + d4 + 1], acc.y);
        atomicAdd(&sums[(size_t)cur * DIM + d4 + 2], acc.z);
        atomicAdd(&sums[(size_t)cur * DIM + d4 + 3], acc.w);
    }
}

__global__ __launch_bounds__(256) void k_gate_fp(const float* __restrict__ x,
                                                 const int* __restrict__ batch,
                                                 const __hip_bfloat16* __restrict__ Wt2,
                                                 const float* __restrict__ nu,
                                                 const float* __restrict__ gpart,
                                                 float* __restrict__ xout,
                                                 int n) {
    __shared__ __align__(16) char sA[32 * 512];
    const int tid  = threadIdx.x;
    const int wave = tid >> 6;
    const int lane = tid & 63;
    const int r15  = lane & 15;
    const int kq   = lane >> 4;
    const int i0   = blockIdx.x * 32;

    float4 av0[4], av1[4];
    #pragma unroll
    for (int j = 0; j < 4; ++j) {
        int v = j * 256 + tid;
        int r = v >> 5;
        int k8 = v & 31;
        int node = i0 + r;
        if (node < n) {
            const float* p = x + (size_t)node * DIM + k8 * 8;
            av0[j] = *(const float4*)p;
            av1[j] = *(const float4*)(p + 4);
        } else {
            av0[j] = make_float4(0.f, 0.f, 0.f, 0.f);
            av1[j] = av0[j];
        }
    }
    #pragma unroll
    for (int j = 0; j < 4; ++j) {
        int v = j * 256 + tid;
        int r = v >> 5;
        int k8 = v & 31;
        uint4 pk;
        pk.x = pack2bf(av0[j].x, av0[j].y);
        pk.y = pack2bf(av0[j].z, av0[j].w);
        pk.z = pack2bf(av1[j].x, av1[j].y);
        pk.w = pack2bf(av1[j].z, av1[j].w);
        *(uint4*)(sA + r * 512 + ((k8 * 16) ^ ((r & 7) << 4))) = pk;
    }
    __syncthreads();

    f32x4 acc[2][4];
    #pragma unroll
    for (int m = 0; m < 2; ++m)
        #pragma unroll
        for (int nn = 0; nn < 4; ++nn)
            acc[m][nn] = (f32x4){0.f, 0.f, 0.f, 0.f};

    #pragma unroll
    for (int ks = 0; ks < 8; ++ks) {
        bf16x8 a[2], b[4];
        #pragma unroll
        for (int nn = 0; nn < 4; ++nn) {
            int c = wave * 64 + nn * 16 + r15;
            b[nn] = *(const bf16x8*)(Wt2 + ((size_t)(ks * 4 + kq) << 11) + (c << 3));
        }
        #pragma unroll
        for (int m = 0; m < 2; ++m) {
            int r = m * 16 + r15;
            a[m] = *(const bf16x8*)(sA + r * 512 + ((ks * 64 + kq * 16) ^ ((r & 7) << 4)));
        }
        #pragma unroll
        for (int m = 0; m < 2; ++m)
            #pragma unroll
            for (int nn = 0; nn < 4; ++nn)
                acc[m][nn] = __builtin_amdgcn_mfma_f32_16x16x32_bf16(a[m], b[nn], acc[m][nn], 0, 0, 0);
    }

    #pragma unroll
    for (int m = 0; m < 2; ++m) {
        #pragma unroll
        for (int q = 0; q < 4; ++q) {
            int rr = m * 16 + kq * 4 + q;
            int node = i0 + rr;
            if (node >= n) continue;
            int bb = batch[node];
            #pragma unroll
            for (int nn = 0; nn < 4; ++nn) {
                int col = wave * 64 + nn * 16 + r15;
                float pre = acc[m][nn][q] + gpart[bb * DIM + col];
                float e = __expf(-pre);
                float gte = __builtin_amdgcn_rcpf(1.0f + e);
                float xres = __bfloat162float(
                    *(const __hip_bfloat16*)(sA + rr * 512 + ((2 * col) ^ ((rr & 7) << 4))));
                xout[(size_t)node * DIM + col] = xres + gte * nu[bb * DIM + col];
            }
        }
    }
}

extern "C" void kernel_launch(void* const* d_in, const int* in_sizes, int n_in,
                              void* d_out, int out_size, void* d_ws, size_t ws_size,
                              hipStream_t stream) {
    const float* x        = (const float*)d_in[0];
    const int*   batch    = (const int*)d_in[1];
    const float* vn_embed = (const float*)d_in[2];
    const float* W1  = (const float*)d_in[3];
    const float* b1  = (const float*)d_in[4];
    const float* g1  = (const float*)d_in[5];
    const float* be1 = (const float*)d_in[6];
    const float* W2  = (const float*)d_in[7];
    const float* b2  = (const float*)d_in[8];
    const float* g2  = (const float*)d_in[9];
    const float* be2 = (const float*)d_in[10];
    const float* Wg  = (const float*)d_in[11];
    const float* bg  = (const float*)d_in[12];

    const int n = in_sizes[0] / DIM;
    const int nt32 = (n + 31) / 32;
    const int nt64 = (n + 63) / 64;

    float* out = (float*)d_out;
    float* xout = out;                              // [N,D]
    float* vn_state_out = out + (size_t)n * DIM;    // [B,D]

    // ws layout
    char* wsb = (char*)d_ws;
    int*   seg_start = (int*)wsb;                               // 4 KB
    float* extra     = (float*)(wsb + 4096);                    // 512 KB [B][D]
    float* part      = (float*)(wsb + 4096 + 524288);           // nt32 * 1 KB
    char*  after     = wsb + 4096 + 524288 + (size_t)nt32 * DIM * 4;
    float* nu    = (float*)after;                               // 512 KB
    float* gpart = nu + (size_t)B_SEG * DIM;                    // 512 KB
    __hip_bfloat16* Wt2 = (__hip_bfloat16*)(gpart + (size_t)B_SEG * DIM); // 128 KB
    __hip_bfloat16* xbf = Wt2 + (size_t)DIM * DIM;

    const size_t xbf_off = (size_t)((char*)xbf - wsb);
    const size_t need = xbf_off + (size_t)nt64 * 64 * 512;
    const bool use_bf = (ws_size >= need);

    k_prep<<<385, 256, 0, stream>>>(Wg, Wt2, batch, seg_start, extra, n);

    if (use_bf) {
        k_pass1<<<nt32, 256, 0, stream>>>(x, batch, part, extra, xbf, n);
    } else {
        k_segsum_fp<<<nt64, 256, 0, stream>>>(x, batch, extra, n);
    }

    k_vn<<<B_SEG, 256, 0, stream>>>(part, extra, seg_start, vn_embed,
                                    W1, b1, g1, be1,
                                    W2, b2, g2, be2,
                                    Wg, bg,
                                    vn_state_out, nu, gpart,
                                    use_bf ? 1 : 0);

    if (use_bf) {
        k_gate_bf<<<nt64, 256, 0, stream>>>(xbf, batch, Wt2, nu, gpart, xout, n);
    } else {
        int nblk3 = (n + 31) / 32;
        k_gate_fp<<<nblk3, 256, 0, stream>>>(x, batch, Wt2, nu, gpart, xout, n);
    }
}